// Round 5
// baseline (533.509 us; speedup 1.0000x reference)
//
#include <hip/hip_runtime.h>

// GraphConv: B=16, S=50000, FIN=FOUT=16, T=64, E=8M
// R5: R4 post-mortem — write amplification scales with #runs (R3 2M runs/965MB,
// R4 1M runs/715MB): byte-granular appends of ~8-rec runs are line-hostile.
// Two-level radix: part1 coarse (row>>14, 49 bins, runs ~167 recs -> clean
// writes) then part2 (8192-rec tiles of coarse-sorted recs -> ~16 fine keys
// -> runs ~512 recs -> clean) producing the fine-contiguous layout k_pull
// already consumes. buf2 chunked by coarse-bin ranges if ws is tight.
#define BNUM 16
#define NCOL 800000   // S*FIN
#define NROW 800000   // S*FOUT
#define RPB  1024     // fine rows per bin (pull tile == block size)
#define HB   1024     // fine bin count (10-bit key)
#define NFINE 784     // used fine bins = 49*16
#define CSH  14       // coarse shift (16384 rows)
#define NC   49       // coarse bins
#define CB   64       // padded coarse bin count (6-bit key)
#define PR   8192     // edges/recs per part block
#define CAP  11264    // pull LDS capacity (mean 10240, +10 sigma)

// ---- bf16 <-> f32 helpers (bit-exact RNE) ----
__device__ __forceinline__ unsigned short f2bf(float f) {
    unsigned u = __float_as_uint(f);
    unsigned r = (u + 0x7fffu + ((u >> 16) & 1u)) >> 16;   // round-nearest-even
    return (unsigned short)r;
}
__device__ __forceinline__ float bf2f(unsigned short h) {
    return __uint_as_float(((unsigned)h) << 16);
}

// ballot-based equal-key mask + rank within group (wave-parallel, no atomics)
template <int BITS>
__device__ __forceinline__ void brank(unsigned key, bool v, int lane,
                                      int& rank, int& gsz) {
    unsigned long long vm = __ballot(v);
    unsigned long long eq = ~0ull;
#pragma unroll
    for (int b = 0; b < BITS; ++b) {
        unsigned long long bb = __ballot((key >> b) & 1u);
        eq &= ((key >> b) & 1u) ? bb : ~bb;
    }
    eq &= vm;
    rank = __popcll(eq & ((1ull << lane) - 1ull));
    gsz  = __popcll(eq);
}

// x [16][800000] f32 (b-major) -> xT [800000][16] bf16 (c-major, 32B per c)
__global__ __launch_bounds__(256) void k_transpose_x(const float* __restrict__ x,
                                                     unsigned* __restrict__ xT) {
    int c = blockIdx.x * 256 + threadIdx.x;
    if (c >= NCOL) return;
    unsigned p[8];
#pragma unroll
    for (int b = 0; b < 8; ++b) {
        float lo = x[(size_t)(2 * b)     * NCOL + c];
        float hi = x[(size_t)(2 * b + 1) * NCOL + c];
        p[b] = (unsigned)f2bf(lo) | ((unsigned)f2bf(hi) << 16);
    }
    uint4* dst = reinterpret_cast<uint4*>(xT + (size_t)c * 8);
    dst[0] = make_uint4(p[0], p[1], p[2], p[3]);
    dst[1] = make_uint4(p[4], p[5], p[6], p[7]);
}

// Ballot-based per-wave histogram of FINE row bins (row>>10).
__global__ __launch_bounds__(1024) void k_hist(const int* __restrict__ rows,
                                               unsigned* __restrict__ gcount,
                                               int E) {
    __shared__ unsigned short h16[16][HB];      // 32KB wave-private
    int tid = threadIdx.x, lane = tid & 63, wv = tid >> 6;
    unsigned* hw = (unsigned*)h16;
    for (int i = tid; i < 16 * HB / 2; i += 1024) hw[i] = 0u;
    __syncthreads();
    int c0 = blockIdx.x * PR;
#pragma unroll
    for (int c = 0; c < 8; ++c) {
        int idx = c0 + c * 1024 + tid;
        bool v = idx < E;
        unsigned key = 0u;
        if (v) key = (unsigned)__builtin_nontemporal_load(rows + idx) >> 10;
        int rank, gsz;
        brank<10>(key, v, lane, rank, gsz);
        if (v && rank == 0)
            h16[wv][key] = (unsigned short)(h16[wv][key] + (unsigned)gsz);
    }
    __syncthreads();
    for (int b = tid; b < HB; b += 1024) {
        unsigned s = 0;
#pragma unroll
        for (int ww = 0; ww < 16; ++ww) s += h16[ww][b];
        if (s) atomicAdd(&gcount[b], s);
    }
}

// Exclusive scan of 2048 zero-padded fine counts -> offs + fine cursor init.
__global__ __launch_bounds__(1024) void k_scan(const unsigned* __restrict__ gcount,
                                               unsigned* __restrict__ offs,
                                               unsigned* __restrict__ cursorF) {
    __shared__ unsigned wsum[16];
    int t = threadIdx.x;
    unsigned a0 = gcount[2 * t], a1 = gcount[2 * t + 1];
    unsigned ts = a0 + a1, incl = ts;
    for (int off = 1; off < 64; off <<= 1) {
        unsigned n = __shfl_up(incl, off, 64);
        if ((t & 63) >= off) incl += n;
    }
    if ((t & 63) == 63) wsum[t >> 6] = incl;
    __syncthreads();
    unsigned pre = 0;
    for (int k = 0; k < (t >> 6); ++k) pre += wsum[k];
    unsigned ex = pre + incl - ts;
    offs[2 * t] = ex;       offs[2 * t + 1] = ex + a0;
    cursorF[2 * t] = ex;    cursorF[2 * t + 1] = ex + a0;
    if (t == 1023) offs[2048] = pre + incl;
}

// coarse offsets = fine offs at multiples of 16; init coarse cursor.
__global__ __launch_bounds__(64) void k_coarse(const unsigned* __restrict__ offs,
                                               unsigned* __restrict__ coffs,
                                               unsigned* __restrict__ cursor1) {
    int t = threadIdx.x;
    if (t <= NC) coffs[t] = offs[t * 16];
    if (t <  NC) cursor1[t] = offs[t * 16];
}

// Pass 1: coarse multisplit by row>>14 (49 bins, runs ~167 recs).
// recA1 = col | type<<20 | (row>>16)<<26 ; recB1 = row & 0xFFFF.
__global__ __launch_bounds__(1024) void k_part1(const int* __restrict__ rows,
                                                const int* __restrict__ cols,
                                                const int* __restrict__ et,
                                                unsigned* __restrict__ cursor1,
                                                unsigned* __restrict__ recA1,
                                                unsigned short* __restrict__ recB1,
                                                int E) {
    __shared__ unsigned short h16[16][CB];      // 2KB wave-private hist/cursor
    __shared__ unsigned srtP[PR];               // 32KB payload
    __shared__ unsigned srtK[PR];               // 32KB raw row
    __shared__ unsigned gadj[CB];

    int tid = threadIdx.x, lane = tid & 63, wv = tid >> 6;
    int c0 = blockIdx.x * PR;
    unsigned* hw = (unsigned*)h16;
    for (int i = tid; i < 16 * CB / 2; i += 1024) hw[i] = 0u;
    __syncthreads();

    unsigned er[8], ec[8];
#pragma unroll
    for (int c = 0; c < 8; ++c) {
        int idx = c0 + c * 1024 + tid;
        if (idx < E) {
            unsigned r  = (unsigned)__builtin_nontemporal_load(rows + idx);
            unsigned cc = (unsigned)__builtin_nontemporal_load(cols + idx);
            unsigned ty = (unsigned)__builtin_nontemporal_load(et + idx);
            er[c] = r;
            ec[c] = cc | (ty << 20) | ((r >> 16) << 26);
        } else {
            er[c] = 0xFFFFFFFFu; ec[c] = 0u;
        }
    }

    // phase A
#pragma unroll
    for (int c = 0; c < 8; ++c) {
        bool v = er[c] != 0xFFFFFFFFu;
        unsigned key = (er[c] >> CSH) & (CB - 1);
        int rank, gsz;
        brank<6>(key, v, lane, rank, gsz);
        if (v && rank == 0)
            h16[wv][key] = (unsigned short)(h16[wv][key] + (unsigned)gsz);
    }
    __syncthreads();

    // scan 64 bins in wave 0 + global reservation
    if (tid < CB) {
        unsigned t0 = 0;
#pragma unroll
        for (int ww = 0; ww < 16; ++ww) {
            unsigned a = h16[ww][tid]; h16[ww][tid] = (unsigned short)t0; t0 += a;
        }
        unsigned incl = t0;
        for (int off = 1; off < 64; off <<= 1) {
            unsigned n = __shfl_up(incl, off, 64);
            if (tid >= off) incl += n;
        }
        unsigned ex = incl - t0;
        gadj[tid] = (t0 ? atomicAdd(&cursor1[tid], t0) : 0u) - ex;
#pragma unroll
        for (int ww = 0; ww < 16; ++ww)
            h16[ww][tid] = (unsigned short)(h16[ww][tid] + ex);
    }
    __syncthreads();

    // phase B: place into LDS sorted order
#pragma unroll
    for (int c = 0; c < 8; ++c) {
        bool v = er[c] != 0xFFFFFFFFu;
        unsigned key = (er[c] >> CSH) & (CB - 1);
        int rank, gsz;
        brank<6>(key, v, lane, rank, gsz);
        unsigned cur = h16[wv][key];
        if (v && rank == 0)
            h16[wv][key] = (unsigned short)(cur + (unsigned)gsz);
        if (v) {
            unsigned d = cur + (unsigned)rank;
            srtP[d] = ec[c];
            srtK[d] = er[c];
        }
    }
    __syncthreads();

    // flush long runs (avg ~167 recs) -> near-line-clean writes
    int tot = min(PR, E - c0);
    for (int j = tid; j < tot; j += 1024) {
        unsigned rr = srtK[j], key = rr >> CSH;
        unsigned dst = gadj[key] + (unsigned)j;
        recA1[dst] = srtP[j];
        recB1[dst] = (unsigned short)(rr & 0xFFFFu);
    }
}

// Pass 2: fine multisplit (row>>10) of coarse-sorted recs. A tile of 8192
// recs sits inside ~1 coarse bin -> ~16 fine keys -> runs ~512 recs.
// Writes recA2 = col|type<<20, recB2 = row & 1023 at offs - chunk base.
__global__ __launch_bounds__(1024) void k_part2(const unsigned* __restrict__ recA1,
                                                const unsigned short* __restrict__ recB1,
                                                unsigned* __restrict__ cursorF,
                                                const unsigned* __restrict__ coffs,
                                                unsigned* __restrict__ recA2,
                                                unsigned short* __restrict__ recB2,
                                                int c0, int c1, unsigned cap) {
    __shared__ unsigned short h16[16][HB];      // 32KB
    __shared__ unsigned srtP[PR];               // 32KB payload (col|type)
    __shared__ unsigned srtK[PR];               // 32KB row
    __shared__ unsigned gadj[HB];               // 4KB
    __shared__ unsigned wsum[16];

    unsigned base = coffs[c0];
    unsigned endr = coffs[c1];
    unsigned beg  = base + (unsigned)blockIdx.x * PR;
    if (beg >= endr) return;
    int tot = (int)min((unsigned)PR, endr - beg);

    int tid = threadIdx.x, lane = tid & 63, wv = tid >> 6;
    unsigned* hw = (unsigned*)h16;
    for (int i = tid; i < 16 * HB / 2; i += 1024) hw[i] = 0u;
    __syncthreads();

    unsigned er[8], ec[8];
#pragma unroll
    for (int c = 0; c < 8; ++c) {
        int idx = c * 1024 + tid;
        if (idx < tot) {
            unsigned a = __builtin_nontemporal_load(recA1 + beg + idx);
            unsigned b = __builtin_nontemporal_load(recB1 + beg + idx);
            er[c] = ((a >> 26) << 16) | b;          // full row
            ec[c] = a & 0x03FFFFFFu;                // col | type<<20
        } else {
            er[c] = 0xFFFFFFFFu; ec[c] = 0u;
        }
    }

    // phase A
#pragma unroll
    for (int c = 0; c < 8; ++c) {
        bool v = er[c] != 0xFFFFFFFFu;
        unsigned key = (er[c] >> 10) & (HB - 1);
        int rank, gsz;
        brank<10>(key, v, lane, rank, gsz);
        if (v && rank == 0)
            h16[wv][key] = (unsigned short)(h16[wv][key] + (unsigned)gsz);
    }
    __syncthreads();

    // scan 1024 bins (1/thread) + global fine reservation (rebased to chunk)
    {
        int b = tid;
        unsigned t0 = 0;
#pragma unroll
        for (int ww = 0; ww < 16; ++ww) {
            unsigned a = h16[ww][b]; h16[ww][b] = (unsigned short)t0; t0 += a;
        }
        unsigned incl = t0;
        for (int off = 1; off < 64; off <<= 1) {
            unsigned n = __shfl_up(incl, off, 64);
            if ((tid & 63) >= off) incl += n;
        }
        if ((tid & 63) == 63) wsum[tid >> 6] = incl;
        __syncthreads();
        unsigned pre = 0;
        for (int k = 0; k < (tid >> 6); ++k) pre += wsum[k];
        unsigned ex = pre + incl - t0;
        gadj[b] = (t0 ? atomicAdd(&cursorF[b], t0) : 0u) - base - ex;
#pragma unroll
        for (int ww = 0; ww < 16; ++ww)
            h16[ww][b] = (unsigned short)(h16[ww][b] + ex);
    }
    __syncthreads();

    // phase B
#pragma unroll
    for (int c = 0; c < 8; ++c) {
        bool v = er[c] != 0xFFFFFFFFu;
        unsigned key = (er[c] >> 10) & (HB - 1);
        int rank, gsz;
        brank<10>(key, v, lane, rank, gsz);
        unsigned cur = h16[wv][key];
        if (v && rank == 0)
            h16[wv][key] = (unsigned short)(cur + (unsigned)gsz);
        if (v) {
            unsigned d = cur + (unsigned)rank;
            srtP[d] = ec[c];
            srtK[d] = er[c];
        }
    }
    __syncthreads();

    // flush runs ~512 recs
    for (int j = tid; j < tot; j += 1024) {
        unsigned rr = srtK[j], key = (rr >> 10) & (HB - 1);
        unsigned dst = gadj[key] + (unsigned)j;
        if (dst < cap) {
            recA2[dst] = srtP[j];
            recB2[dst] = (unsigned short)(rr & 1023u);
        }
    }
}

__device__ __forceinline__ void fma8(float* a, float wt, uint4 v, int base) {
    a[base + 0] += wt * bf2f((unsigned short)(v.x & 0xffffu));
    a[base + 1] += wt * bf2f((unsigned short)(v.x >> 16));
    a[base + 2] += wt * bf2f((unsigned short)(v.y & 0xffffu));
    a[base + 3] += wt * bf2f((unsigned short)(v.y >> 16));
    a[base + 4] += wt * bf2f((unsigned short)(v.z & 0xffffu));
    a[base + 5] += wt * bf2f((unsigned short)(v.z >> 16));
    a[base + 6] += wt * bf2f((unsigned short)(v.w & 0xffffu));
    a[base + 7] += wt * bf2f((unsigned short)(v.w >> 16));
}

// One block per 1024-row fine bin (R4-proven): ballot counting-sort by lrow,
// 1 thread/row register accumulate, coalesced store. Rec indices rebased by
// the chunk base coffs[c0].
__global__ __launch_bounds__(1024) void k_pull(const unsigned* __restrict__ offs,
                                               const unsigned* __restrict__ recA2,
                                               const unsigned short* __restrict__ recB2,
                                               const float* __restrict__ wt_tab,
                                               const unsigned* __restrict__ xT,
                                               float* __restrict__ out,
                                               const unsigned* __restrict__ coffs,
                                               int c0, int fine_base) {
    __shared__ unsigned short h16[16][RPB];    // 32KB wave-private hist/cursor
    __shared__ unsigned srt[CAP];              // 44KB sorted payload
    __shared__ unsigned short ptr_[RPB + 1];   // 2KB row offsets
    __shared__ unsigned wsum[16];

    int tid = threadIdx.x, lane = tid & 63, wv = tid >> 6;
    int bin = fine_base + blockIdx.x;
    unsigned base  = coffs[c0];
    unsigned beg_g = offs[bin];
    unsigned end_g = offs[bin + 1];
    int total = (int)(end_g - beg_g);
    int n   = min(total, CAP);
    int lb  = (int)(beg_g - base);             // chunk-local base
    int nr  = (n + 1023) >> 10;

    unsigned* hw = (unsigned*)h16;
    for (int i = tid; i < 16 * RPB / 2; i += 1024) hw[i] = 0u;
    __syncthreads();

    // phase A: ballot histogram by lrow
    for (int c = 0; c < nr; ++c) {
        int idx = c * 1024 + tid;
        bool v = idx < n;
        unsigned key = 0u;
        if (v) key = recB2[lb + idx] & (RPB - 1u);
        int rank, gsz;
        brank<10>(key, v, lane, rank, gsz);
        if (v && rank == 0)
            h16[wv][key] = (unsigned short)(h16[wv][key] + (unsigned)gsz);
    }
    __syncthreads();

    // scan 1024 row-bins
    {
        unsigned t0 = 0;
#pragma unroll
        for (int ww = 0; ww < 16; ++ww) {
            unsigned a = h16[ww][tid]; h16[ww][tid] = (unsigned short)t0; t0 += a;
        }
        unsigned incl = t0;
        for (int off = 1; off < 64; off <<= 1) {
            unsigned m = __shfl_up(incl, off, 64);
            if ((tid & 63) >= off) incl += m;
        }
        if ((tid & 63) == 63) wsum[tid >> 6] = incl;
        __syncthreads();
        unsigned pre = 0;
        for (int k = 0; k < (tid >> 6); ++k) pre += wsum[k];
        unsigned ex = pre + incl - t0;
        ptr_[tid] = (unsigned short)ex;
        if (tid == 1023) ptr_[RPB] = (unsigned short)n;
#pragma unroll
        for (int ww = 0; ww < 16; ++ww)
            h16[ww][tid] = (unsigned short)(h16[ww][tid] + ex);
    }
    __syncthreads();

    // phase B: reload (L2-hot), place payload into LDS sorted order
    for (int c = 0; c < nr; ++c) {
        int idx = c * 1024 + tid;
        bool v = idx < n;
        unsigned key = 0u, pay = 0u;
        if (v) {
            key = recB2[lb + idx] & (RPB - 1u);
            pay = recA2[lb + idx];
        }
        int rank, gsz;
        brank<10>(key, v, lane, rank, gsz);
        unsigned cur = h16[wv][key];
        if (v && rank == 0)
            h16[wv][key] = (unsigned short)(cur + (unsigned)gsz);
        if (v) srt[cur + (unsigned)rank] = pay;
    }
    __syncthreads();

    // gather: 1 thread per row, register accumulate, 2-deep pipeline
    bool ovf = total > CAP;
    int r = tid;
    float a[16];
#pragma unroll
    for (int k = 0; k < 16; ++k) a[k] = 0.f;
    {
        int p0 = (int)ptr_[r];
        int p1 = (int)ptr_[r + 1];
        uint4 lo = make_uint4(0, 0, 0, 0), hi = lo;
        unsigned u = 0u;
        int p = p0;
        if (p < p1) {
            u = srt[p];
            const uint4* q = reinterpret_cast<const uint4*>(xT + (size_t)(u & 0xFFFFFu) * 8);
            lo = q[0]; hi = q[1];
        }
        while (p < p1) {
            int pn = p + 1;
            unsigned un = 0u;
            uint4 lon = make_uint4(0, 0, 0, 0), hin = lon;
            if (pn < p1) {
                un = srt[pn];
                const uint4* qn = reinterpret_cast<const uint4*>(xT + (size_t)(un & 0xFFFFFu) * 8);
                lon = qn[0]; hin = qn[1];
            }
            float wt = wt_tab[u >> 20];
            fma8(a, wt, lo, 0);
            fma8(a, wt, hi, 8);
            u = un; lo = lon; hi = hin; p = pn;
        }
    }
    int gr = bin * RPB + r;
    if (gr < NROW) {
        if (!ovf) {
#pragma unroll
            for (int k = 0; k < 16; ++k)
                __builtin_nontemporal_store(a[k], out + (size_t)k * NROW + gr);
        } else {
#pragma unroll
            for (int k = 0; k < 16; ++k)
                out[(size_t)k * NROW + gr] = a[k];
        }
    }

    // overflow safety (statistically never)
    if (ovf) {
        __syncthreads();
        for (int i = CAP + tid; i < total; i += 1024) {
            unsigned uu = recA2[lb + i];
            unsigned lr = recB2[lb + i] & (RPB - 1u);
            int gr2 = bin * RPB + (int)lr;
            if (gr2 >= NROW) continue;
            float wt = wt_tab[uu >> 20];
            const uint4* q = reinterpret_cast<const uint4*>(xT + (size_t)(uu & 0xFFFFFu) * 8);
            uint4 vlo = q[0], vhi = q[1];
            float tmp[16];
#pragma unroll
            for (int k = 0; k < 16; ++k) tmp[k] = 0.f;
            fma8(tmp, wt, vlo, 0);
            fma8(tmp, wt, vhi, 8);
#pragma unroll
            for (int k = 0; k < 16; ++k)
                atomicAdd(out + (size_t)k * NROW + gr2, tmp[k]);
        }
    }
}

// ---------------- fallback path (atomic scatter, needs only 51.2MB) ----

__global__ __launch_bounds__(256) void k_scatter(const int* __restrict__ rows,
                                                 const int* __restrict__ cols,
                                                 const int* __restrict__ et,
                                                 const float* __restrict__ w,
                                                 const unsigned* __restrict__ xT,
                                                 unsigned short* __restrict__ outT,
                                                 int E) {
    long long tid = (long long)blockIdx.x * 256 + threadIdx.x;
    long long e = tid >> 3;
    if (e >= E) return;
    int j = (int)(tid & 7);
    int r = __builtin_nontemporal_load(rows + e);
    int c = __builtin_nontemporal_load(cols + e);
    int t = __builtin_nontemporal_load(et + e);
    float wt = w[t];
    unsigned px = xT[(size_t)c * 8 + j];
    float x0 = bf2f((unsigned short)(px & 0xffffu));
    float x1 = bf2f((unsigned short)(px >> 16));
    unsigned short b0 = f2bf(wt * x0);
    unsigned short b1 = f2bf(wt * x1);
    unsigned data = (unsigned)b0 | ((unsigned)b1 << 16);
    unsigned short* dst = outT + ((size_t)r * 16 + 2 * j);
    asm volatile("global_atomic_pk_add_bf16 %0, %1, off"
                 :: "v"(dst), "v"(data) : "memory");
}

__global__ __launch_bounds__(256) void k_transpose_out(const unsigned* __restrict__ outT,
                                                       float* __restrict__ out) {
    int r = blockIdx.x * 256 + threadIdx.x;
    if (r >= NROW) return;
    const uint4* src = reinterpret_cast<const uint4*>(outT + (size_t)r * 8);
    uint4 v0 = src[0], v1 = src[1];
    unsigned p[8] = {v0.x, v0.y, v0.z, v0.w, v1.x, v1.y, v1.z, v1.w};
#pragma unroll
    for (int b = 0; b < 8; ++b) {
        out[(size_t)(2 * b)     * NROW + r] = bf2f((unsigned short)(p[b] & 0xffffu));
        out[(size_t)(2 * b + 1) * NROW + r] = bf2f((unsigned short)(p[b] >> 16));
    }
}

extern "C" void kernel_launch(void* const* d_in, const int* in_sizes, int n_in,
                              void* d_out, int out_size, void* d_ws, size_t ws_size,
                              hipStream_t stream) {
    const float* x    = (const float*)d_in[0];
    const float* w    = (const float*)d_in[1];
    const int*   rows = (const int*)d_in[2];
    const int*   cols = (const int*)d_in[3];
    const int*   et   = (const int*)d_in[4];
    const int    E    = in_sizes[2];

    float* out = (float*)d_out;

    // ws layout: xT 25.6MB | recA1 u32 | recB1 u16 | aux | buf2 (chunked)
    size_t xT_b    = (size_t)NCOL * 8 * 4;
    size_t b1A_off = xT_b;
    size_t b1B_off = b1A_off + (size_t)E * 4;
    size_t aux_off = (b1B_off + (size_t)E * 2 + 255) & ~(size_t)255;
    // aux words: gcount[2048] offs[2049] cursorF[2048] coffs[64] cursor1[64]
    size_t aux_words = 2048 + 2049 + 2048 + 64 + 64;
    size_t b2_off  = (aux_off + aux_words * 4 + 255) & ~(size_t)255;

    // pick chunk count so buf2 fits
    int nchunk = 0, cpk = NC;
    size_t capN = 0;
    if (ws_size > b2_off) {
        size_t avail = ws_size - b2_off;
        for (int nc = 1; nc <= 8; ++nc) {
            int c = (NC + nc - 1) / nc;
            size_t cn = (size_t)(((long long)E * c + NC - 1) / NC) + 65536;
            if (cn * 6 + 64 <= avail) { nchunk = nc; cpk = c; capN = cn; break; }
        }
    }

    unsigned* xT = (unsigned*)d_ws;

    if (nchunk) {
        unsigned*       recA1   = (unsigned*)((char*)d_ws + b1A_off);
        unsigned short* recB1   = (unsigned short*)((char*)d_ws + b1B_off);
        unsigned*       gcount  = (unsigned*)((char*)d_ws + aux_off);
        unsigned*       offs    = gcount + 2048;
        unsigned*       cursorF = offs + 2049;
        unsigned*       coffs   = cursorF + 2048;
        unsigned*       cursor1 = coffs + 64;
        unsigned*       recA2   = (unsigned*)((char*)d_ws + b2_off);
        unsigned short* recB2   = (unsigned short*)((char*)d_ws + b2_off + capN * 4);

        hipMemsetAsync(gcount, 0, 2048 * 4, stream);
        k_transpose_x<<<NCOL / 256, 256, 0, stream>>>(x, xT);

        int pblocks = (E + PR - 1) / PR;
        k_hist<<<pblocks, 1024, 0, stream>>>(rows, gcount, E);
        k_scan<<<1, 1024, 0, stream>>>(gcount, offs, cursorF);
        k_coarse<<<1, 64, 0, stream>>>(offs, coffs, cursor1);
        k_part1<<<pblocks, 1024, 0, stream>>>(rows, cols, et, cursor1, recA1, recB1, E);

        for (int k = 0; k < nchunk; ++k) {
            int c0 = k * cpk;
            if (c0 >= NC) break;
            int c1 = min(c0 + cpk, NC);
            k_part2<<<pblocks, 1024, 0, stream>>>(recA1, recB1, cursorF, coffs,
                                                  recA2, recB2, c0, c1, (unsigned)capN);
            k_pull<<<(c1 - c0) * 16, 1024, 0, stream>>>(offs, recA2, recB2, w, xT, out,
                                                        coffs, c0, c0 * 16);
        }
    } else {
        // fallback: pk_add_bf16 atomic scatter (51.2MB ws)
        unsigned short* outT = (unsigned short*)d_ws;
        unsigned*       xT2  = (unsigned*)((char*)d_ws + (size_t)NROW * BNUM * 2);

        hipMemsetAsync(outT, 0, (size_t)NROW * BNUM * 2, stream);
        k_transpose_x<<<NCOL / 256, 256, 0, stream>>>(x, xT2);

        long long total = (long long)E * 8;
        int blocks = (int)((total + 255) / 256);
        k_scatter<<<blocks, 256, 0, stream>>>(rows, cols, et, w, xT2, outT, E);
        k_transpose_out<<<NROW / 256, 256, 0, stream>>>((const unsigned*)outT, out);
    }
}